// Round 8
// baseline (4320.813 us; speedup 1.0000x reference)
//
#include <hip/hip_runtime.h>

// ---------------------------------------------------------------------------
// dLSTM R8 = R7 with the two real bugs fixed.
// R4-R7 post-mortem: compiler REMATERIALIZED the "VGPR-resident" weights
// (VGPR_Count==128 == exactly the weight regs; loads sunk into the loop), so
// weights were re-fetched from HBM every phase (R6 FETCH 3.53GB = 13.8MB x
// 256 phases) -> invariant 13.6us/phase, and the sunk loads corrupted R7's
// hand-counted vmcnt schedule -> NaN. R7's issue order was also wrong.
// Fixes: (1) pin vA/vB with empty `asm("" : "+v")` -> remat impossible,
// true residency; (2) DMA groups issued in consume order {A0,A1,W}(k),
// prologue 4 groups, steady vmcnt(9), tails 6/3/0, 4-slot rings, no alias.
// ---------------------------------------------------------------------------

typedef __attribute__((ext_vector_type(8))) short short8;
typedef __attribute__((ext_vector_type(4))) short short4v;
typedef __attribute__((ext_vector_type(4))) float f32x4;

#define MFMA16(a, b, c) __builtin_amdgcn_mfma_f32_16x16x32_bf16((a), (b), (c), 0, 0, 0)
#define GDMA(gp, lp)                                                        \
  __builtin_amdgcn_global_load_lds(                                         \
      (const __attribute__((address_space(1))) unsigned int*)(gp),          \
      (__attribute__((address_space(3))) unsigned int*)(lp), 16, 0, 0)

static constexpr int BATCH = 32;
static constexpr int HID = 2048;
static constexpr int NWG = 256;
static constexpr int NTHR = 512;           // 8 waves
static constexpr int BH = BATCH * HID;     // 65536
static constexpr size_t WMAT = (size_t)8192 * 2048;
// LDS: [0,32K) W-ring 4KB/wave | [32K,96K) A-ring 8KB/wave | [96K,112K) red
static constexpr int LDS_WRING = 0;
static constexpr int LDS_ARING = 32768;
static constexpr int LDS_RED = 98304;
static constexpr int LDS_BYTES = 114688;   // 112 KB

#define AT_ADD(p, v) __hip_atomic_fetch_add((p), (v), __ATOMIC_RELAXED, __HIP_MEMORY_SCOPE_AGENT)
#define AT_LD(p) __hip_atomic_load((p), __ATOMIC_RELAXED, __HIP_MEMORY_SCOPE_AGENT)
#define AT_ST(p, v) __hip_atomic_store((p), (v), __ATOMIC_RELAXED, __HIP_MEMORY_SCOPE_AGENT)

__device__ __forceinline__ unsigned short f2bf(float x) {
  unsigned u = __float_as_uint(x);
  u += 0x7FFFu + ((u >> 16) & 1u);
  return (unsigned short)(u >> 16);
}
__device__ __forceinline__ float sigm(float x) { return 1.f / (1.f + __expf(-x)); }
__device__ __forceinline__ float tanh_(float x) {
  float e = __expf(2.f * x);
  return 1.f - 2.f / (e + 1.f);
}

__global__ void cvt_bf16_k(const float* __restrict__ s, unsigned short* __restrict__ d,
                           long n4) {
  long i = blockIdx.x * (long)blockDim.x + threadIdx.x;
  long st = (long)gridDim.x * blockDim.x;
  for (; i < n4; i += st) {
    float4 v = ((const float4*)s)[i];
    short4v o;
    o.x = (short)f2bf(v.x); o.y = (short)f2bf(v.y);
    o.z = (short)f2bf(v.z); o.w = (short)f2bf(v.w);
    ((short4v*)d)[i] = o;
  }
}

// Wout f32 [2048][2048] -> WoutT bf16 transposed
__global__ void tcvt_k(const float* __restrict__ src, unsigned short* __restrict__ dst) {
  __shared__ float T[64][65];
  const int jb = blockIdx.x * 64, kb = blockIdx.y * 64;
  const int tid = threadIdx.x;
#pragma unroll
  for (int r = 0; r < 4; ++r) {
    const int row = r * 16 + (tid >> 4), c4 = (tid & 15) * 4;
    float4 v = *(const float4*)&src[(size_t)(jb + row) * 2048 + kb + c4];
    T[row][c4] = v.x; T[row][c4 + 1] = v.y; T[row][c4 + 2] = v.z; T[row][c4 + 3] = v.w;
  }
  __syncthreads();
#pragma unroll
  for (int r = 0; r < 4; ++r) {
    const int k = r * 16 + (tid >> 4), j4 = (tid & 15) * 4;
    short4v o;
    o.x = (short)f2bf(T[j4][k]);     o.y = (short)f2bf(T[j4 + 1][k]);
    o.z = (short)f2bf(T[j4 + 2][k]); o.w = (short)f2bf(T[j4 + 3][k]);
    *(short4v*)&dst[(size_t)(kb + k) * 2048 + jb + j4] = o;
  }
}

// Wfp(packed) = A[8192x2048] . Bt[2048x2048]^T ; grid(64,16), 4 waves (2x2)
__global__ void gemm_pack_k(const unsigned short* __restrict__ A,
                            const unsigned short* __restrict__ Bt,
                            unsigned short* __restrict__ Wfp) {
  __shared__ __align__(16) unsigned short As[128][72], Bs[128][72];
  const int tid = threadIdx.x, wv = tid >> 6, lane = tid & 63;
  const int wm = wv >> 1, wn = wv & 1;
  const int g0 = blockIdx.x * 128, k0 = blockIdx.y * 128;
  f32x4 acc[4][4];
#pragma unroll
  for (int i = 0; i < 4; ++i)
#pragma unroll
    for (int j = 0; j < 4; ++j) acc[i][j] = (f32x4){0.f, 0.f, 0.f, 0.f};

  for (int kt = 0; kt < 32; ++kt) {
#pragma unroll
    for (int rr = 0; rr < 4; ++rr) {
      const int row = rr * 32 + (tid >> 3), c8 = (tid & 7) * 8;
      *(short8*)&As[row][c8] = *(const short8*)&A[(size_t)(g0 + row) * 2048 + kt * 64 + c8];
      *(short8*)&Bs[row][c8] = *(const short8*)&Bt[(size_t)(k0 + row) * 2048 + kt * 64 + c8];
    }
    __syncthreads();
#pragma unroll
    for (int kk = 0; kk < 2; ++kk) {
      short8 af[4], bf[4];
#pragma unroll
      for (int mi = 0; mi < 4; ++mi)
        af[mi] = *(const short8*)&As[wm * 64 + mi * 16 + (lane & 15)][kk * 32 + (lane >> 4) * 8];
#pragma unroll
      for (int ni = 0; ni < 4; ++ni)
        bf[ni] = *(const short8*)&Bs[wn * 64 + ni * 16 + (lane & 15)][kk * 32 + (lane >> 4) * 8];
#pragma unroll
      for (int mi = 0; mi < 4; ++mi)
#pragma unroll
        for (int ni = 0; ni < 4; ++ni)
          acc[mi][ni] = MFMA16(af[mi], bf[ni], acc[mi][ni]);
    }
    __syncthreads();
  }
#pragma unroll
  for (int mi = 0; mi < 4; ++mi)
#pragma unroll
    for (int ni = 0; ni < 4; ++ni)
#pragma unroll
      for (int r = 0; r < 4; ++r) {
        const int g = g0 + wm * 64 + mi * 16 + (lane >> 4) * 4 + r;
        const int k = k0 + wn * 64 + ni * 16 + (lane & 15);
        const int gateblk = g >> 11, gcol = g & 2047;
        const int wgp = gcol >> 3, nn = (gcol & 7) + 8 * (gateblk & 1), tile = gateblk >> 1;
        const int kblk = k >> 5, e = k & 7, lane_p = nn + 16 * ((k >> 3) & 3);
        Wfp[(((size_t)(wgp * 2 + tile) * 64 + kblk) * 64 + lane_p) * 8 + e] =
            f2bf(acc[mi][ni][r]);
      }
}

__global__ void pack_W1_k(const float* __restrict__ src, unsigned short* __restrict__ dst) {
  const int bid = blockIdx.x;              // 512: [wg(256)][tile(2)]
  const int wg = bid >> 1, tile = bid & 1;
  const int tid = threadIdx.x;
  __shared__ __align__(16) unsigned short L[16][2056];
  for (int i = tid; i < 16 * 512; i += 256) {
    const int r = i >> 9, c4 = i & 511;
    const int gr = tile * 4096 + (r < 8 ? wg * 8 + r : 2048 + wg * 8 + r - 8);
    float4 v = ((const float4*)(src + (size_t)gr * 2048))[c4];
    short4v o;
    o.x = (short)f2bf(v.x); o.y = (short)f2bf(v.y);
    o.z = (short)f2bf(v.z); o.w = (short)f2bf(v.w);
    *(short4v*)&L[r][c4 * 4] = o;
  }
  __syncthreads();
  short8* dchunks = (short8*)dst;
  const size_t cbase = (size_t)(wg * 2 + tile) * 64;
  for (int c = tid; c < 4096; c += 256) {
    const int lane = c & 63, kblk = c >> 6;
    const int nn = lane & 15, kb = (lane >> 4) << 3;
    short8 v = *(const short8*)&L[nn][kblk * 32 + kb];
    dchunks[(cbase + kblk) * 64 + lane] = v;
  }
}

__global__ void bias_k(const float* __restrict__ Wih, const float* __restrict__ bout,
                       const float* __restrict__ bih, const float* __restrict__ bhh,
                       float* bA0, float* bAf, float* bB) {
  const int g = blockIdx.x * 8 + (threadIdx.x >> 6);
  const int lane = threadIdx.x & 63;
  float s = 0.f;
  for (int i = 0; i < 32; ++i)
    s += Wih[(size_t)g * 2048 + i * 64 + lane] * bout[i * 64 + lane];
  for (int off = 32; off; off >>= 1) s += __shfl_down(s, off);
  if (lane == 0) {
    const float b0 = bih[g] + bhh[g];
    bA0[g] = b0; bAf[g] = b0 + s;
    bB[g] = bih[8192 + g] + bhh[8192 + g];
  }
}

__global__ void init_k(const float* __restrict__ h0, const float* __restrict__ c0,
                       unsigned short* h0p, unsigned short* h1p, unsigned short* zbuf,
                       float* c0f, float* c1f, unsigned* bar) {
  int i = blockIdx.x * blockDim.x + threadIdx.x;
  if (i < BH) {
    const int e = i & 7, lane = (i >> 3) & 63, kblk = (i >> 9) & 63, mtile = i >> 15;
    const int m = mtile * 16 + (lane & 15);
    const int k = kblk * 32 + ((lane >> 4) << 3) + e;
    h0p[i] = f2bf(h0[m * HID + k]);
    h1p[i] = f2bf(h0[BH + m * HID + k]);
    zbuf[i] = 0;
    c0f[i] = c0[i];
    c1f[i] = c0[BH + i];
  }
  if (i < 320) bar[i] = 0u;
}

// R4-proven hierarchical fence barrier (8 groups of 32 -> master -> epoch)
__device__ __forceinline__ void grid_barrier(unsigned* bar, int bno) {
  asm volatile("s_waitcnt vmcnt(0)" ::: "memory");
  __syncthreads();
  if (threadIdx.x == 0) {
    __builtin_amdgcn_fence(__ATOMIC_RELEASE, "agent");
    const int g = blockIdx.x >> 5;
    unsigned a = AT_ADD(&bar[g * 32], 1u);
    if (a == (unsigned)(32 * bno - 1)) {
      unsigned m = AT_ADD(&bar[256], 1u);
      if (m == (unsigned)(8 * bno - 1)) AT_ST(&bar[288], (unsigned)bno);
    }
    while (AT_LD(&bar[288]) < (unsigned)bno) __builtin_amdgcn_s_sleep(2);
    __builtin_amdgcn_fence(__ATOMIC_ACQUIRE, "agent");
  }
  __syncthreads();
}

// ---- phase: tile0-B from pinned VGPRs; tile1-B + A via global_load_lds -----
// groups issued in CONSUME order: G(k) = {A_even(k), A_odd(k), W(k)}.
// prologue G0..G3 (12 ops); end of iter k (k<12) issues G(k+4).
// wait before consuming G(k): vmcnt(9) k<=12, 6 @13, 3 @14, 0 @15.
#define PHASE(VARR, WMATP, CBUF, HOUTP, OUTP, BSEL)                               \
  {                                                                               \
    const char* Ab = (const char*)Asrc + ((size_t)(s * 16)) * 1024 + lane * 16;   \
    const char* Wb = (const char*)(WMATP) +                                       \
                     (((size_t)(wg * 2 + 1) * 64) + s * 16) * 1024 + lane * 16;   \
    _Pragma("unroll")                                                             \
    for (int g = 0; g < 4; ++g) {                                                 \
      GDMA(Ab + (size_t)g * 1024,         lds3 + aring + g * 2048);               \
      GDMA(Ab + 65536 + (size_t)g * 1024, lds3 + aring + g * 2048 + 1024);        \
      GDMA(Wb + (size_t)g * 1024,         lds3 + wring + g * 1024);               \
    }                                                                             \
    f32x4 acc00 = {0.f, 0.f, 0.f, 0.f}, acc01 = acc00, acc10 = acc00, acc11 = acc00; \
    _Pragma("unroll")                                                             \
    for (int k = 0; k < 16; ++k) {                                                \
      if (k <= 12)      { asm volatile("s_waitcnt vmcnt(9)" ::: "memory"); }      \
      else if (k == 13) { asm volatile("s_waitcnt vmcnt(6)" ::: "memory"); }      \
      else if (k == 14) { asm volatile("s_waitcnt vmcnt(3)" ::: "memory"); }      \
      else              { asm volatile("s_waitcnt vmcnt(0)" ::: "memory"); }      \
      __builtin_amdgcn_sched_barrier(0);                                          \
      short8 a0 = *(const short8*)(smem + aring + (k & 3) * 2048 + lane * 16);    \
      short8 a1 = *(const short8*)(smem + aring + (k & 3) * 2048 + 1024 + lane * 16); \
      short8 b1 = *(const short8*)(smem + wring + (k & 3) * 1024 + lane * 16);    \
      short8 b0 = VARR[k];                                                        \
      acc00 = MFMA16(a0, b0, acc00); acc01 = MFMA16(a1, b0, acc01);               \
      acc10 = MFMA16(a0, b1, acc10); acc11 = MFMA16(a1, b1, acc11);               \
      __builtin_amdgcn_sched_barrier(0);                                          \
      if (k < 12) {                                                               \
        GDMA(Ab + (size_t)(k + 4) * 1024,         lds3 + aring + ((k + 4) & 3) * 2048); \
        GDMA(Ab + 65536 + (size_t)(k + 4) * 1024, lds3 + aring + ((k + 4) & 3) * 2048 + 1024); \
        GDMA(Wb + (size_t)(k + 4) * 1024,         lds3 + wring + ((k + 4) & 3) * 1024); \
      }                                                                           \
    }                                                                             \
    __syncthreads();                                                              \
    *(f32x4*)&red[((w * 2 + 0) * 64 + lane) * 4] = acc00;                         \
    *(f32x4*)&red[((w * 2 + 1) * 64 + lane) * 4] = acc01;                         \
    __syncthreads();                                                              \
    float gi = 0.f, gf_ = 0.f;                                                    \
    if (tid < 256) {                                                              \
      const int b = tid >> 3, cc = tid & 7, m = b >> 4, br = b & 15;              \
      const int reg = br & 3, lb = (br >> 2) << 4;                                \
      _Pragma("unroll")                                                           \
      for (int ww = 0; ww < 8; ++ww) {                                            \
        gi  += red[((ww * 2 + m) * 64 + lb + cc) * 4 + reg];                      \
        gf_ += red[((ww * 2 + m) * 64 + lb + cc + 8) * 4 + reg];                  \
      }                                                                           \
    }                                                                             \
    __syncthreads();                                                              \
    *(f32x4*)&red[((w * 2 + 0) * 64 + lane) * 4] = acc10;                         \
    *(f32x4*)&red[((w * 2 + 1) * 64 + lane) * 4] = acc11;                         \
    __syncthreads();                                                              \
    if (tid < 256) {                                                              \
      const int b = tid >> 3, cc = tid & 7, m = b >> 4, br = b & 15;              \
      const int reg = br & 3, lb = (br >> 2) << 4;                                \
      float gg = 0.f, go = 0.f;                                                   \
      _Pragma("unroll")                                                           \
      for (int ww = 0; ww < 8; ++ww) {                                            \
        gg += red[((ww * 2 + m) * 64 + lb + cc) * 4 + reg];                       \
        go += red[((ww * 2 + m) * 64 + lb + cc + 8) * 4 + reg];                   \
      }                                                                           \
      const int col = wg * 8 + cc;                                                \
      gi  += (BSEL)[col];                                                         \
      gf_ += (BSEL)[2048 + col];                                                  \
      gg  += (BSEL)[4096 + col];                                                  \
      go  += (BSEL)[6144 + col];                                                  \
      const float iv = sigm(gi), fv = sigm(gf_), gv = tanh_(gg), ov = sigm(go);   \
      const float cold = (CBUF)[b * HID + col];                                   \
      const float cnew = fv * cold + iv * gv;                                     \
      const float hnew = ov * tanh_(cnew);                                        \
      (CBUF)[b * HID + col] = cnew;                                               \
      const int kblk = col >> 5, lh = (col >> 3) & 3, e = col & 7;                \
      const int lane_p = (b & 15) | (lh << 4), mt = b >> 4;                       \
      (HOUTP)[((size_t)(mt * 64 + kblk) * 64 + lane_p) * 8 + e] = f2bf(hnew);     \
      if (OUTP) ((float*)(OUTP))[b * HID + col] = hnew;                           \
    }                                                                             \
  }

__global__ __launch_bounds__(NTHR, 2) void lstm_persist(
    const unsigned short* __restrict__ Wfp, const unsigned short* __restrict__ Wh0p,
    const unsigned short* __restrict__ Wi1p, const unsigned short* __restrict__ Wh1p,
    const float* __restrict__ bA0, const float* __restrict__ bAf,
    const float* __restrict__ bB,
    unsigned short* h0p, unsigned short* h1p, const unsigned short* zbuf,
    float* c0f, float* c1f, float* __restrict__ out, int T, unsigned* bar) {
  extern __shared__ __align__(16) char smem[];
  auto* lds3 = (__attribute__((address_space(3))) char*)smem;
  float* red = (float*)(smem + LDS_RED);
  const int wg = blockIdx.x, tid = threadIdx.x;
  const int w = tid >> 6, lane = tid & 63;
  const int p = w >> 2, s = w & 3;
  const int wring = LDS_WRING + w * 4096;
  const int aring = LDS_ARING + w * 8192;
  const unsigned short* M0 = p ? Wh0p : Wfp;
  const unsigned short* M1 = p ? Wh1p : Wi1p;

  // VGPR-resident weights: tile0 of M0 (phase A) and M1 (phase B): 128 VGPRs.
  short8 vA[16], vB[16];
  {
    const short8* m0c = (const short8*)M0;
    const short8* m1c = (const short8*)M1;
#pragma unroll
    for (int c = 0; c < 16; ++c)
      vA[c] = m0c[(((size_t)(wg * 2 + 0) * 64) + s * 16 + c) * 64 + lane];
#pragma unroll
    for (int c = 0; c < 16; ++c)
      vB[c] = m1c[(((size_t)(wg * 2 + 0) * 64) + s * 16 + c) * 64 + lane];
  }
  // PIN: make values opaque -> no rematerialization, no sunk reloads.
#pragma unroll
  for (int c = 0; c < 16; ++c) {
    asm volatile("" : "+v"(vA[c]));
    asm volatile("" : "+v"(vB[c]));
  }
  asm volatile("s_waitcnt vmcnt(0)" ::: "memory");  // clean vmcnt baseline
  __builtin_amdgcn_sched_barrier(0);

  int bno = 1;
  for (int t = 0; t < T; ++t) {
    const int par = t & 1;
    {  // phase A: gates0 = Wfused*h1(t-1) + Whh0*h0(t-1) -> h0(t), c0
      const unsigned short* Asrc =
          (p == 0) ? ((t == 0) ? zbuf : h1p + par * BH) : (h0p + par * BH);
      const float* bsel = (t == 0) ? bA0 : bAf;
      PHASE(vA, M0, c0f, h0p + (par ^ 1) * BH, (float*)nullptr, bsel)
    }
    grid_barrier(bar, bno++);
    {  // phase B: gates1 = Wih1*h0(t) + Whh1*h1(t-1) -> h1(t), c1, out(t)
      const unsigned short* Asrc = (p == 0) ? (h0p + (par ^ 1) * BH) : (h1p + par * BH);
      PHASE(vB, M1, c1f, h1p + (par ^ 1) * BH, out + (size_t)t * BH, bB)
    }
    grid_barrier(bar, bno++);
  }
}

extern "C" void kernel_launch(void* const* d_in, const int* in_sizes, int n_in,
                              void* d_out, int out_size, void* d_ws, size_t ws_size,
                              hipStream_t stream) {
  const float* h0 = (const float*)d_in[0];
  const float* c0 = (const float*)d_in[1];
  const float* Wih = (const float*)d_in[2];
  const float* Whh = (const float*)d_in[3];
  const float* bih = (const float*)d_in[4];
  const float* bhh = (const float*)d_in[5];
  const float* Wout = (const float*)d_in[6];
  const float* bout = (const float*)d_in[7];
  float* out = (float*)d_out;
  const int T = out_size / BH;

  unsigned short* Wfp = (unsigned short*)d_ws;
  unsigned short* Wh0p = Wfp + WMAT;
  unsigned short* Wi1p = Wfp + 2 * WMAT;
  unsigned short* Wh1p = Wfp + 3 * WMAT;
  unsigned short* tmpA = Wi1p;    // alias, dead after gemm_pack_k
  unsigned short* WoutT = Wh1p;   // alias, dead after gemm_pack_k
  unsigned short* S = Wfp + 4 * WMAT;
  unsigned short* h0p = S;                   // 2 x 65536 ping-pong
  unsigned short* h1p = S + 131072;          // 2 x 65536
  unsigned short* zbuf = S + 262144;         // 65536
  float* F = (float*)(S + 327680);
  float* c0f = F;
  float* c1f = F + 65536;
  float* bA0 = F + 131072;
  float* bAf = F + 139264;
  float* bB = F + 147456;
  unsigned* bar = (unsigned*)(F + 155648);   // 320 u32

  cvt_bf16_k<<<2048, 256, 0, stream>>>(Wih, tmpA, (long)(WMAT / 4));
  tcvt_k<<<dim3(32, 32), 256, 0, stream>>>(Wout, WoutT);
  gemm_pack_k<<<dim3(64, 16), 256, 0, stream>>>(tmpA, WoutT, Wfp);
  pack_W1_k<<<512, 256, 0, stream>>>(Whh, Wh0p);
  pack_W1_k<<<512, 256, 0, stream>>>(Wih + WMAT, Wi1p);
  pack_W1_k<<<512, 256, 0, stream>>>(Whh + WMAT, Wh1p);
  bias_k<<<1024, 512, 0, stream>>>(Wih, bout, bih, bhh, bA0, bAf, bB);
  init_k<<<256, 256, 0, stream>>>(h0, c0, h0p, h1p, zbuf, c0f, c1f, bar);

  (void)hipFuncSetAttribute((const void*)lstm_persist,
                            hipFuncAttributeMaxDynamicSharedMemorySize, LDS_BYTES);
  lstm_persist<<<NWG, NTHR, LDS_BYTES, stream>>>(Wfp, Wh0p, Wi1p, Wh1p,
                                                 bA0, bAf, bB,
                                                 h0p, h1p, zbuf, c0f, c1f, out, T, bar);
}